// Round 13
// baseline (165.460 us; speedup 1.0000x reference)
//
#include <hip/hip_runtime.h>

#define GROUPS 1920

// Intra-wave LDS fence: A's ds_writes drain before same-wave B's ds_reads.
// Correctness of same-wave cross-lane LDS exchange w/o s_barrier proven by r12.
#define WAVE_LDS_FENCE() asm volatile("s_waitcnt lgkmcnt(0)" ::: "memory")

// ---------------------------------------------------------------------------
// LDS swizzle (row stride 32 floats, XOR on the float4-slot index).
// ---------------------------------------------------------------------------
__device__ __forceinline__ int rh(int r) { return (r + (r >> 3)) & 7; }
__device__ __forceinline__ int swz(int r, int c) {
    return (r << 5) + ((((c >> 2) ^ rh(r)) << 2) | (c & 3));
}
__device__ __forceinline__ int swz4(int r, int c4) {   // aligned float4 slot
    return (r << 5) + ((c4 ^ rh(r)) << 2);
}

// ---------- phase A (wave-split): Ut[k][4p of tile pt] = sum_q A[q][p]*X[k][q] ----------
// Wave w owns p-tiles pt = w*3 + {0,1,2} (4 cols each -> cols 0..23 across 2 waves).
template<int DIN, int KR>
__device__ __forceinline__ void layerA2w(const float* bufIn, float* Ut,
                                         const float* A, int w, int l)
{
    constexpr int NL = (DIN / KR) * 3;
    if (l < NL) {
        const int kt = l / 3;
        const int pt = w * 3 + (l - kt * 3);
        float acc[KR][4];
        #pragma unroll
        for (int j = 0; j < KR; ++j)
            #pragma unroll
            for (int a = 0; a < 4; ++a) acc[j][a] = 0.f;
        #pragma unroll 2
        for (int q = 0; q < 22; ++q) {
            const float4 a0 = *(const float4*)(A + q * 28 + pt * 4);  // 112|16 ok
            float xv[KR];
            #pragma unroll
            for (int j = 0; j < KR; ++j) xv[j] = bufIn[swz(kt * KR + j, q)];
            #pragma unroll
            for (int j = 0; j < KR; ++j) {
                acc[j][0] = fmaf(xv[j], a0.x, acc[j][0]);
                acc[j][1] = fmaf(xv[j], a0.y, acc[j][1]);
                acc[j][2] = fmaf(xv[j], a0.z, acc[j][2]);
                acc[j][3] = fmaf(xv[j], a0.w, acc[j][3]);
            }
        }
        #pragma unroll
        for (int j = 0; j < KR; ++j)
            *(float4*)(Ut + swz4(kt * KR + j, pt)) =
                make_float4(acc[j][0], acc[j][1], acc[j][2], acc[j][3]);
    }
}

// ---------- phase B (wave-split): bufOut[c][4p] = relu(b + sum_k Ut[k][4p]*W[k][c]) ----------
// Reads Ut cols of its OWN wave only -> no block barrier after A (fence only).
template<int DIN, int DOUT, int CR>
__device__ __forceinline__ void layerB2w(const float* __restrict__ W,
                                         const float* __restrict__ Bb,
                                         const float* Ut, float* bufOut,
                                         int w, int l)
{
    constexpr int NL = (DOUT / CR) * 3;
    if (l < NL) {
        const int ct = l / 3;
        const int pt = w * 3 + (l - ct * 3);
        const int c0 = ct * CR;
        float acc[CR][4];
        #pragma unroll
        for (int b = 0; b < CR; ++b) {
            const float bias = Bb[c0 + b];
            #pragma unroll
            for (int a = 0; a < 4; ++a) acc[b][a] = bias;
        }
        #pragma unroll 4
        for (int k = 0; k < DIN; ++k) {
            const float4 u0 = *(const float4*)(Ut + swz4(k, pt));
            float wv[CR];
            if constexpr (CR == 1) {
                wv[0] = W[k * DOUT + c0];
            } else if constexpr (CR == 2) {
                const float2 w2 = *(const float2*)(W + k * DOUT + c0);
                wv[0] = w2.x; wv[1] = w2.y;
            } else {
                #pragma unroll
                for (int b = 0; b < CR; b += 4) {
                    const float4 w4 = *(const float4*)(W + k * DOUT + c0 + b);
                    wv[b] = w4.x; wv[b + 1] = w4.y; wv[b + 2] = w4.z; wv[b + 3] = w4.w;
                }
            }
            #pragma unroll
            for (int b = 0; b < CR; ++b) {
                acc[b][0] = fmaf(wv[b], u0.x, acc[b][0]);
                acc[b][1] = fmaf(wv[b], u0.y, acc[b][1]);
                acc[b][2] = fmaf(wv[b], u0.z, acc[b][2]);
                acc[b][3] = fmaf(wv[b], u0.w, acc[b][3]);
            }
        }
        #pragma unroll
        for (int b = 0; b < CR; ++b)
            *(float4*)(bufOut + swz4(c0 + b, pt)) =
                make_float4(fmaxf(acc[b][0], 0.f), fmaxf(acc[b][1], 0.f),
                            fmaxf(acc[b][2], 0.f), fmaxf(acc[b][3], 0.f));
    }
}

// Round 13: wave-split p-tiles + H-buffer ping-pong -> barriers 13 -> 7
// (only before cross-wave-read phases), both waves active in every phase
// (B3/B4/A4 serial issue halved). bufA (32 rows): X, H2, pool partials;
// bufB (64 rows): H1, H3. All cross-wave hazards covered by barrier-before-A.
__global__ __launch_bounds__(128, 4) void gcn_kernel(
    const float* __restrict__ x, const float* __restrict__ ea,
    const float* __restrict__ W1, const float* __restrict__ b1,
    const float* __restrict__ W2, const float* __restrict__ b2,
    const float* __restrict__ W3, const float* __restrict__ b3,
    const float* __restrict__ W4, const float* __restrict__ b4,
    float* __restrict__ pT)       // [16*152][128]
{
    __shared__ __align__(16) float sA[24 * 28];       // [q][p], stride 28
    __shared__ float dv[24];
    __shared__ __align__(16) float bufA[32 * 32];     // X(14r), H2(32r), pscr
    __shared__ __align__(16) float bufB[64 * 32];     // H1(16r), H3(64r)
    __shared__ __align__(16) float Ut[64 * 32];

    const int tid = threadIdx.x;
    const int g = blockIdx.x;                         // group 0..1919
    const int b = g / 120, t = g - b * 120;
    const int w = tid >> 6, l = tid & 63;

    // ---- folded pad zeroing: slots 0..3 (t==0 block) / 124..127 (t==119) ----
    if (t == 0)
        for (int j = tid; j < 152 * 4; j += 128)
            pT[(((size_t)(b * 152) + (j >> 2)) << 7) + (j & 3)] = 0.f;
    if (t == 119)
        for (int j = tid; j < 152 * 4; j += 128)
            pT[(((size_t)(b * 152) + (j >> 2)) << 7) + 124 + (j & 3)] = 0.f;

    // ---- A fill: (q,p) edge weight q->p, 1 on diag, 0 pads ----
    for (int idx = tid; idx < 24 * 28; idx += 128) {
        const int q = idx / 28, p = idx - q * 28;
        float v = 0.f;
        if (q < 22 && p < 22) {
            if (q == p) v = 1.0f;
            else {
                const int e = q * 21 + p - (p > q);
                v = ea[((size_t)g * 462 + e) * 5 + 4];
            }
        }
        sA[idx] = v;
    }
    // ---- x -> bufA (swizzled): Xt[k][p] ----
    for (int idx = tid; idx < 14 * 24; idx += 128) {
        const int k = idx / 24, p = idx - k * 24;
        bufA[swz(k, p)] = (p < 22) ? x[((size_t)g * 22 + p) * 14 + k] : 0.f;
    }
    __syncthreads();

    if (tid < 24) {   // dinv per dst p: column sum (self-loop incl.)
        const int p = tid;
        float s = 0.f;
        #pragma unroll
        for (int q = 0; q < 22; ++q) s += sA[q * 28 + p];
        dv[p] = (s > 0.f) ? rsqrtf(s) : 0.f;
    }
    __syncthreads();
    for (int idx = tid; idx < 24 * 28; idx += 128) {
        const int q = idx / 28, p = idx - q * 28;
        if (p < 24) sA[idx] *= dv[q] * dv[p];
    }
    __syncthreads();

    layerA2w<14, 1>(bufA, Ut, sA, w, l);          WAVE_LDS_FENCE();
    layerB2w<14, 16, 1>(W1, b1, Ut, bufB, w, l);  __syncthreads();
    layerA2w<16, 1>(bufB, Ut, sA, w, l);          WAVE_LDS_FENCE();
    layerB2w<16, 32, 2>(W2, b2, Ut, bufA, w, l);  __syncthreads();
    layerA2w<32, 2>(bufA, Ut, sA, w, l);          WAVE_LDS_FENCE();
    layerB2w<32, 64, 4>(W3, b3, Ut, bufB, w, l);  __syncthreads();
    layerA2w<64, 4>(bufB, Ut, sA, w, l);          WAVE_LDS_FENCE();

    // ---- layer 4 phase B fused with mean-pool; partials -> bufA (dead) ----
    // 57 lanes/wave (ct 0..18 x 3 p-tiles), both waves active.
    float* pscr = bufA;     // [6][152] partials, 912 <= 1024 floats
    if (l < 19 * 3) {
        const int ct = l / 3;
        const int pt = w * 3 + (l - ct * 3);
        const int c0 = ct * 8;
        float acc[8][4];
        #pragma unroll
        for (int bb = 0; bb < 8; ++bb) {
            const float bias = b4[c0 + bb];
            #pragma unroll
            for (int a = 0; a < 4; ++a) acc[bb][a] = bias;
        }
        #pragma unroll 2
        for (int k = 0; k < 64; ++k) {
            const float4 u0 = *(const float4*)(Ut + swz4(k, pt));
            const float4 wa = *(const float4*)(W4 + k * 152 + c0);
            const float4 wb = *(const float4*)(W4 + k * 152 + c0 + 4);
            const float wv[8] = {wa.x, wa.y, wa.z, wa.w, wb.x, wb.y, wb.z, wb.w};
            #pragma unroll
            for (int bb = 0; bb < 8; ++bb) {
                acc[bb][0] = fmaf(wv[bb], u0.x, acc[bb][0]);
                acc[bb][1] = fmaf(wv[bb], u0.y, acc[bb][1]);
                acc[bb][2] = fmaf(wv[bb], u0.z, acc[bb][2]);
                acc[bb][3] = fmaf(wv[bb], u0.w, acc[bb][3]);
            }
        }
        const int alim = (pt == 5) ? 2 : 4;   // mask pad cols 22,23
        float ps[8];
        #pragma unroll
        for (int bb = 0; bb < 8; ++bb) {
            float s = 0.f;
            #pragma unroll
            for (int a = 0; a < 4; ++a)
                s += (a < alim) ? fmaxf(acc[bb][a], 0.f) : 0.f;
            ps[bb] = s;
        }
        *(float4*)(pscr + pt * 152 + c0)     = make_float4(ps[0], ps[1], ps[2], ps[3]);
        *(float4*)(pscr + pt * 152 + c0 + 4) = make_float4(ps[4], ps[5], ps[6], ps[7]);
    }
    __syncthreads();

    {   // transposed store: pT[b*152+c][4+t]
        float* basep = pT + (((size_t)(b * 152)) << 7) + 4 + t;
        for (int c = tid; c < 152; c += 128) {
            const float s = ((((pscr[c] + pscr[152 + c]) + pscr[304 + c])
                            + pscr[456 + c]) + pscr[608 + c]) + pscr[760 + c];
            basep[(size_t)c << 7] = s * (1.0f / 22.0f);
        }
    }
}

// conv+BN+sigmoid+capsnorm (unchanged from round 11): 544 blocks x 512 thr,
// wave = (d-quad, i-half); w scalar-pipe, f lane-coalesced; LDS combine.
__global__ __launch_bounds__(512) void conv_caps_kernel(
    const float* __restrict__ pT, const float* __restrict__ cw,
    const float* __restrict__ cb, const float* __restrict__ gamma,
    const float* __restrict__ beta, float* __restrict__ out)
{
    __shared__ float sp[8 * 4 * 64];        // [wave][acc j][lane]

    const int bx = blockIdx.x;              // 544 = 16 * 34
    const int b = bx / 34, r = bx - b * 34;
    const int n = r >> 1, thalf = r & 1;
    const int tid = threadIdx.x;
    const int w8 = __builtin_amdgcn_readfirstlane(tid >> 6);   // 0..7, SGPR
    const int dq = w8 >> 1, ih = w8 & 1;    // d-quad, i-half (both uniform)
    const int lane = tid & 63;
    const bool act = (lane < 60);
    const int tt = act ? (thalf * 60 + lane) : 119;   // clamp idle lanes

    const int o0 = dq * 68 + n;             // (dq*4)*17 + n, uniform
    float a0 = ih ? 0.f : cb[o0];
    float a1 = ih ? 0.f : cb[o0 + 17];
    float a2 = ih ? 0.f : cb[o0 + 34];
    float a3 = ih ? 0.f : cb[o0 + 51];

    const float* pf  = pT + (((size_t)(b * 152 + ih * 76)) << 7) + 3 + tt;
    const float* wp0 = cw + (size_t)o0 * 456 + ih * 228;   // uniform scalar ptrs
    const float* wp1 = wp0 + 17 * 456;
    const float* wp2 = wp0 + 34 * 456;
    const float* wp3 = wp0 + 51 * 456;

    for (int ib = 0; ib < 19; ++ib) {       // 19 chunks x 4 i = 76 channels
        const int iw = ib * 12;
        float wv0[12], wv1[12], wv2[12], wv3[12];
        #pragma unroll
        for (int v = 0; v < 12; ++v) {
            wv0[v] = wp0[iw + v];
            wv1[v] = wp1[iw + v];
            wv2[v] = wp2[iw + v];
            wv3[v] = wp3[iw + v];
        }
        float fv[4][3];
        #pragma unroll
        for (int v = 0; v < 4; ++v) {
            const float* fi = pf + (((size_t)(ib * 4 + v)) << 7);
            fv[v][0] = fi[0]; fv[v][1] = fi[1]; fv[v][2] = fi[2];
        }
        #pragma unroll
        for (int v = 0; v < 4; ++v) {
            const float f0 = fv[v][0], f1 = fv[v][1], f2 = fv[v][2];
            a0 = fmaf(wv0[v*3], f0, fmaf(wv0[v*3+1], f1, fmaf(wv0[v*3+2], f2, a0)));
            a1 = fmaf(wv1[v*3], f0, fmaf(wv1[v*3+1], f1, fmaf(wv1[v*3+2], f2, a1)));
            a2 = fmaf(wv2[v*3], f0, fmaf(wv2[v*3+1], f1, fmaf(wv2[v*3+2], f2, a2)));
            a3 = fmaf(wv3[v*3], f0, fmaf(wv3[v*3+1], f1, fmaf(wv3[v*3+2], f2, a3)));
        }
    }

    sp[(w8 * 4 + 0) * 64 + lane] = a0;
    sp[(w8 * 4 + 1) * 64 + lane] = a1;
    sp[(w8 * 4 + 2) * 64 + lane] = a2;
    sp[(w8 * 4 + 3) * 64 + lane] = a3;
    __syncthreads();

    if (tid < 64) {                         // one wave finishes all 16 d
        const int ln = tid;
        const bool a2c = (ln < 60);
        const int t2 = a2c ? (thalf * 60 + ln) : 119;
        const float sct = gamma[t2] * 0.999500374688f;   // 1/sqrt(1+1e-3)
        const float sht = beta[t2];
        float ss = 0.f;
        #pragma unroll
        for (int q2 = 0; q2 < 4; ++q2) {
            #pragma unroll
            for (int j = 0; j < 4; ++j) {
                const float v = sp[((q2 * 2 + 0) * 4 + j) * 64 + ln]
                              + sp[((q2 * 2 + 1) * 4 + j) * 64 + ln];
                const float z = fmaf(v, sct, sht);
                const float s = 1.0f / (1.0f + __expf(-z));
                const float d = s - 0.5f;
                ss += d * d;
            }
        }
        if (a2c) out[((size_t)b * 120 + t2) * 17 + n] = sqrtf(ss) * 0.5f;
    }
}

extern "C" void kernel_launch(void* const* d_in, const int* in_sizes, int n_in,
                              void* d_out, int out_size, void* d_ws, size_t ws_size,
                              hipStream_t stream) {
    const float* x     = (const float*)d_in[0];
    // d_in[1] edge_index / d_in[2] batch are structurally known -> unused
    const float* ea    = (const float*)d_in[3];
    const float* W1    = (const float*)d_in[4];
    const float* b1    = (const float*)d_in[5];
    const float* W2    = (const float*)d_in[6];
    const float* b2    = (const float*)d_in[7];
    const float* W3    = (const float*)d_in[8];
    const float* b3    = (const float*)d_in[9];
    const float* W4    = (const float*)d_in[10];
    const float* b4    = (const float*)d_in[11];
    const float* cw    = (const float*)d_in[12];
    const float* cb    = (const float*)d_in[13];
    const float* gamma = (const float*)d_in[14];
    const float* beta  = (const float*)d_in[15];
    float* out = (float*)d_out;

    float* pT = (float*)d_ws;                    // [16*152][128] transposed pooled

    hipLaunchKernelGGL(gcn_kernel, dim3(GROUPS), dim3(128), 0, stream,
                       x, ea, W1, b1, W2, b2, W3, b3, W4, b4, pT);
    hipLaunchKernelGGL(conv_caps_kernel, dim3(16 * 34), dim3(512), 0, stream,
                       pT, cw, cb, gamma, beta, out);
}

// Round 14
// 148.489 us; speedup vs baseline: 1.1143x; 1.1143x over previous
//
#include <hip/hip_runtime.h>

#define GROUPS 1920

// ---------------------------------------------------------------------------
// LDS swizzle for the [64 rows][24 cols] X/H/U buffers (row stride 32 floats).
// ---------------------------------------------------------------------------
__device__ __forceinline__ int rh(int r) { return (r + (r >> 3)) & 7; }
__device__ __forceinline__ int swz(int r, int c) {
    return (r << 5) + ((((c >> 2) ^ rh(r)) << 2) | (c & 3));
}
__device__ __forceinline__ int swz4(int r, int c4) {   // aligned float4 slot
    return (r << 5) + ((c4 ^ rh(r)) << 2);
}

// ---------- phase A: Ut[k][p] = sum_q A[q][p] * Xt[k][q] ----------
template<int DIN, int KR>
__device__ __forceinline__ void layerA(const float* buf, float* Ut,
                                       const float* A, int tid)
{
    constexpr int NT = (DIN / KR) * 3;
    if (tid < NT) {
        const int kt = tid / 3, pt = tid - kt * 3;
        const int p0 = pt * 8;
        float acc[KR][8];
        #pragma unroll
        for (int j = 0; j < KR; ++j)
            #pragma unroll
            for (int a = 0; a < 8; ++a) acc[j][a] = 0.f;
        #pragma unroll 2
        for (int q = 0; q < 22; ++q) {
            const float4 a0 = *(const float4*)(A + q * 28 + p0);
            const float4 a1 = *(const float4*)(A + q * 28 + p0 + 4);
            float xv[KR];
            #pragma unroll
            for (int j = 0; j < KR; ++j) xv[j] = buf[swz(kt * KR + j, q)];
            #pragma unroll
            for (int j = 0; j < KR; ++j) {
                acc[j][0] = fmaf(xv[j], a0.x, acc[j][0]);
                acc[j][1] = fmaf(xv[j], a0.y, acc[j][1]);
                acc[j][2] = fmaf(xv[j], a0.z, acc[j][2]);
                acc[j][3] = fmaf(xv[j], a0.w, acc[j][3]);
                acc[j][4] = fmaf(xv[j], a1.x, acc[j][4]);
                acc[j][5] = fmaf(xv[j], a1.y, acc[j][5]);
                acc[j][6] = fmaf(xv[j], a1.z, acc[j][6]);
                acc[j][7] = fmaf(xv[j], a1.w, acc[j][7]);
            }
        }
        #pragma unroll
        for (int j = 0; j < KR; ++j) {
            const int k = kt * KR + j;
            *(float4*)(Ut + swz4(k, pt * 2)) =
                make_float4(acc[j][0], acc[j][1], acc[j][2], acc[j][3]);
            *(float4*)(Ut + swz4(k, pt * 2 + 1)) =
                make_float4(acc[j][4], acc[j][5], acc[j][6], acc[j][7]);
        }
    }
}

// ---------- phase B: buf[c][p] = relu(bias[c] + sum_k Ut[k][p] * W[k][c]) ----------
template<int DIN, int DOUT, int CR>
__device__ __forceinline__ void layerB(const float* __restrict__ W,
                                       const float* __restrict__ Bb,
                                       const float* Ut, float* buf, int tid)
{
    constexpr int NT = (DOUT / CR) * 3;
    if (tid < NT) {
        const int ct = tid / 3, pt = tid - ct * 3;
        const int c0 = ct * CR;
        float acc[CR][8];
        #pragma unroll
        for (int b = 0; b < CR; ++b) {
            const float bias = Bb[c0 + b];
            #pragma unroll
            for (int a = 0; a < 8; ++a) acc[b][a] = bias;
        }
        #pragma unroll 4
        for (int k = 0; k < DIN; ++k) {
            const float4 u0 = *(const float4*)(Ut + swz4(k, pt * 2));
            const float4 u1 = *(const float4*)(Ut + swz4(k, pt * 2 + 1));
            float wv[CR];
            if constexpr (CR == 1) {
                wv[0] = W[k * DOUT + c0];
            } else if constexpr (CR == 2) {
                const float2 w2 = *(const float2*)(W + k * DOUT + c0);
                wv[0] = w2.x; wv[1] = w2.y;
            } else {
                #pragma unroll
                for (int b = 0; b < CR; b += 4) {
                    const float4 w4 = *(const float4*)(W + k * DOUT + c0 + b);
                    wv[b] = w4.x; wv[b + 1] = w4.y; wv[b + 2] = w4.z; wv[b + 3] = w4.w;
                }
            }
            #pragma unroll
            for (int b = 0; b < CR; ++b) {
                acc[b][0] = fmaf(wv[b], u0.x, acc[b][0]);
                acc[b][1] = fmaf(wv[b], u0.y, acc[b][1]);
                acc[b][2] = fmaf(wv[b], u0.z, acc[b][2]);
                acc[b][3] = fmaf(wv[b], u0.w, acc[b][3]);
                acc[b][4] = fmaf(wv[b], u1.x, acc[b][4]);
                acc[b][5] = fmaf(wv[b], u1.y, acc[b][5]);
                acc[b][6] = fmaf(wv[b], u1.z, acc[b][6]);
                acc[b][7] = fmaf(wv[b], u1.w, acc[b][7]);
            }
        }
        #pragma unroll
        for (int b = 0; b < CR; ++b) {
            const int r = c0 + b;
            *(float4*)(buf + swz4(r, pt * 2)) =
                make_float4(fmaxf(acc[b][0], 0.f), fmaxf(acc[b][1], 0.f),
                            fmaxf(acc[b][2], 0.f), fmaxf(acc[b][3], 0.f));
            *(float4*)(buf + swz4(r, pt * 2 + 1)) =
                make_float4(fmaxf(acc[b][4], 0.f), fmaxf(acc[b][5], 0.f),
                            fmaxf(acc[b][6], 0.f), fmaxf(acc[b][7], 0.f));
        }
    }
}

// gcn: round-9 configuration — the measured plateau of this decomposition
// (44-46 us across 6 structural variants; r12 barrier-free and r13 wave-split
// both regressed). 128 thr / 2 waves; per phase the largest KR/CR with
// NT <= 57 (single wave) for minimum LDS wave-instructions.
__global__ __launch_bounds__(128, 4) void gcn_kernel(
    const float* __restrict__ x, const float* __restrict__ ea,
    const float* __restrict__ W1, const float* __restrict__ b1,
    const float* __restrict__ W2, const float* __restrict__ b2,
    const float* __restrict__ W3, const float* __restrict__ b3,
    const float* __restrict__ W4, const float* __restrict__ b4,
    float* __restrict__ pT)       // [16*152][128]
{
    __shared__ __align__(16) float sA[24 * 28];       // [q][p], stride 28
    __shared__ float dv[24];
    __shared__ __align__(16) float buf[64 * 32];      // swizzled [row][24]
    __shared__ __align__(16) float Ut[64 * 32];

    const int tid = threadIdx.x;
    const int g = blockIdx.x;                         // group 0..1919
    const int b = g / 120, t = g - b * 120;

    // ---- folded pad zeroing: slots 0..3 (t==0 block) / 124..127 (t==119) ----
    if (t == 0)
        for (int j = tid; j < 152 * 4; j += 128)
            pT[(((size_t)(b * 152) + (j >> 2)) << 7) + (j & 3)] = 0.f;
    if (t == 119)
        for (int j = tid; j < 152 * 4; j += 128)
            pT[(((size_t)(b * 152) + (j >> 2)) << 7) + 124 + (j & 3)] = 0.f;

    // ---- A fill: (q,p) edge weight q->p, 1 on diag, 0 pads ----
    for (int idx = tid; idx < 24 * 28; idx += 128) {
        const int q = idx / 28, p = idx - q * 28;
        float v = 0.f;
        if (q < 22 && p < 22) {
            if (q == p) v = 1.0f;
            else {
                const int e = q * 21 + p - (p > q);
                v = ea[((size_t)g * 462 + e) * 5 + 4];
            }
        }
        sA[idx] = v;
    }
    // ---- x -> buf (swizzled): Xt[k][p] ----
    for (int idx = tid; idx < 14 * 24; idx += 128) {
        const int k = idx / 24, p = idx - k * 24;
        buf[swz(k, p)] = (p < 22) ? x[((size_t)g * 22 + p) * 14 + k] : 0.f;
    }
    __syncthreads();

    if (tid < 24) {   // dinv per dst p: column sum (self-loop incl.)
        const int p = tid;
        float s = 0.f;
        #pragma unroll
        for (int q = 0; q < 22; ++q) s += sA[q * 28 + p];
        dv[p] = (s > 0.f) ? rsqrtf(s) : 0.f;
    }
    __syncthreads();
    for (int idx = tid; idx < 24 * 28; idx += 128) {
        const int q = idx / 28, p = idx - q * 28;
        if (p < 24) sA[idx] *= dv[q] * dv[p];
    }
    __syncthreads();

    layerA<14, 1>(buf, Ut, sA, tid);           __syncthreads();  // NT=42
    layerB<14, 16, 1>(W1, b1, Ut, buf, tid);   __syncthreads();  // NT=48
    layerA<16, 1>(buf, Ut, sA, tid);           __syncthreads();  // NT=48
    layerB<16, 32, 2>(W2, b2, Ut, buf, tid);   __syncthreads();  // NT=48
    layerA<32, 2>(buf, Ut, sA, tid);           __syncthreads();  // NT=48
    layerB<32, 64, 4>(W3, b3, Ut, buf, tid);   __syncthreads();  // NT=48
    layerA<64, 4>(buf, Ut, sA, tid);           __syncthreads();  // NT=48

    // ---- layer 4 phase B fused with mean-pool, CR=8 -> NT=57, 1 wave ----
    float* pscr = sA;   // [3][152] partials; sA dead after layerA<64> + barrier
    if (tid < 19 * 3) {
        const int ct = tid / 3, pt = tid - ct * 3;
        const int c0 = ct * 8;
        float acc[8][8];
        #pragma unroll
        for (int bb = 0; bb < 8; ++bb) {
            const float bias = b4[c0 + bb];
            #pragma unroll
            for (int a = 0; a < 8; ++a) acc[bb][a] = bias;
        }
        #pragma unroll 2
        for (int k = 0; k < 64; ++k) {
            const float4 u0 = *(const float4*)(Ut + swz4(k, pt * 2));
            const float4 u1 = *(const float4*)(Ut + swz4(k, pt * 2 + 1));
            const float4 wa = *(const float4*)(W4 + k * 152 + c0);
            const float4 wb = *(const float4*)(W4 + k * 152 + c0 + 4);
            const float wv[8] = {wa.x, wa.y, wa.z, wa.w, wb.x, wb.y, wb.z, wb.w};
            #pragma unroll
            for (int bb = 0; bb < 8; ++bb) {
                acc[bb][0] = fmaf(wv[bb], u0.x, acc[bb][0]);
                acc[bb][1] = fmaf(wv[bb], u0.y, acc[bb][1]);
                acc[bb][2] = fmaf(wv[bb], u0.z, acc[bb][2]);
                acc[bb][3] = fmaf(wv[bb], u0.w, acc[bb][3]);
                acc[bb][4] = fmaf(wv[bb], u1.x, acc[bb][4]);
                acc[bb][5] = fmaf(wv[bb], u1.y, acc[bb][5]);
                acc[bb][6] = fmaf(wv[bb], u1.z, acc[bb][6]);
                acc[bb][7] = fmaf(wv[bb], u1.w, acc[bb][7]);
            }
        }
        const int alim = (pt == 2) ? 6 : 8;   // mask pad cols 22,23
        float ps[8];
        #pragma unroll
        for (int bb = 0; bb < 8; ++bb) {
            float s = 0.f;
            #pragma unroll
            for (int a = 0; a < 8; ++a)
                s += (a < alim) ? fmaxf(acc[bb][a], 0.f) : 0.f;
            ps[bb] = s;
        }
        *(float4*)(pscr + pt * 152 + c0)     = make_float4(ps[0], ps[1], ps[2], ps[3]);
        *(float4*)(pscr + pt * 152 + c0 + 4) = make_float4(ps[4], ps[5], ps[6], ps[7]);
    }
    __syncthreads();

    {   // transposed store: pT[b*152+c][4+t]
        float* basep = pT + (((size_t)(b * 152)) << 7) + 4 + t;
        for (int c = tid; c < 152; c += 128) {
            const float s = pscr[c] + pscr[152 + c] + pscr[304 + c];
            basep[(size_t)c << 7] = s * (1.0f / 22.0f);
        }
    }
}

// conv+BN+sigmoid+capsnorm (round 11): 544 blocks x 512 thr (8 waves),
// wave = (d-quad, i-half); w scalar-pipe via readfirstlane-uniform wave id,
// f lane-coalesced; 8-way LDS combine, one wave finishes all 16 d.
__global__ __launch_bounds__(512) void conv_caps_kernel(
    const float* __restrict__ pT, const float* __restrict__ cw,
    const float* __restrict__ cb, const float* __restrict__ gamma,
    const float* __restrict__ beta, float* __restrict__ out)
{
    __shared__ float sp[8 * 4 * 64];        // [wave][acc j][lane]

    const int bx = blockIdx.x;              // 544 = 16 * 34
    const int b = bx / 34, r = bx - b * 34;
    const int n = r >> 1, thalf = r & 1;
    const int tid = threadIdx.x;
    const int w8 = __builtin_amdgcn_readfirstlane(tid >> 6);   // 0..7, SGPR
    const int dq = w8 >> 1, ih = w8 & 1;    // d-quad, i-half (both uniform)
    const int lane = tid & 63;
    const bool act = (lane < 60);
    const int tt = act ? (thalf * 60 + lane) : 119;   // clamp idle lanes

    const int o0 = dq * 68 + n;             // (dq*4)*17 + n, uniform
    float a0 = ih ? 0.f : cb[o0];
    float a1 = ih ? 0.f : cb[o0 + 17];
    float a2 = ih ? 0.f : cb[o0 + 34];
    float a3 = ih ? 0.f : cb[o0 + 51];

    const float* pf  = pT + (((size_t)(b * 152 + ih * 76)) << 7) + 3 + tt;
    const float* wp0 = cw + (size_t)o0 * 456 + ih * 228;   // uniform scalar ptrs
    const float* wp1 = wp0 + 17 * 456;
    const float* wp2 = wp0 + 34 * 456;
    const float* wp3 = wp0 + 51 * 456;

    for (int ib = 0; ib < 19; ++ib) {       // 19 chunks x 4 i = 76 channels
        const int iw = ib * 12;
        float wv0[12], wv1[12], wv2[12], wv3[12];
        #pragma unroll
        for (int v = 0; v < 12; ++v) {
            wv0[v] = wp0[iw + v];
            wv1[v] = wp1[iw + v];
            wv2[v] = wp2[iw + v];
            wv3[v] = wp3[iw + v];
        }
        float fv[4][3];
        #pragma unroll
        for (int v = 0; v < 4; ++v) {
            const float* fi = pf + (((size_t)(ib * 4 + v)) << 7);
            fv[v][0] = fi[0]; fv[v][1] = fi[1]; fv[v][2] = fi[2];
        }
        #pragma unroll
        for (int v = 0; v < 4; ++v) {
            const float f0 = fv[v][0], f1 = fv[v][1], f2 = fv[v][2];
            a0 = fmaf(wv0[v*3], f0, fmaf(wv0[v*3+1], f1, fmaf(wv0[v*3+2], f2, a0)));
            a1 = fmaf(wv1[v*3], f0, fmaf(wv1[v*3+1], f1, fmaf(wv1[v*3+2], f2, a1)));
            a2 = fmaf(wv2[v*3], f0, fmaf(wv2[v*3+1], f1, fmaf(wv2[v*3+2], f2, a2)));
            a3 = fmaf(wv3[v*3], f0, fmaf(wv3[v*3+1], f1, fmaf(wv3[v*3+2], f2, a3)));
        }
    }

    sp[(w8 * 4 + 0) * 64 + lane] = a0;
    sp[(w8 * 4 + 1) * 64 + lane] = a1;
    sp[(w8 * 4 + 2) * 64 + lane] = a2;
    sp[(w8 * 4 + 3) * 64 + lane] = a3;
    __syncthreads();

    if (tid < 64) {                         // one wave finishes all 16 d
        const int ln = tid;
        const bool a2c = (ln < 60);
        const int t2 = a2c ? (thalf * 60 + ln) : 119;
        const float sct = gamma[t2] * 0.999500374688f;   // 1/sqrt(1+1e-3)
        const float sht = beta[t2];
        float ss = 0.f;
        #pragma unroll
        for (int q2 = 0; q2 < 4; ++q2) {
            #pragma unroll
            for (int j = 0; j < 4; ++j) {
                const float v = sp[((q2 * 2 + 0) * 4 + j) * 64 + ln]
                              + sp[((q2 * 2 + 1) * 4 + j) * 64 + ln];
                const float z = fmaf(v, sct, sht);
                const float s = 1.0f / (1.0f + __expf(-z));
                const float d = s - 0.5f;
                ss += d * d;
            }
        }
        if (a2c) out[((size_t)b * 120 + t2) * 17 + n] = sqrtf(ss) * 0.5f;
    }
}

extern "C" void kernel_launch(void* const* d_in, const int* in_sizes, int n_in,
                              void* d_out, int out_size, void* d_ws, size_t ws_size,
                              hipStream_t stream) {
    const float* x     = (const float*)d_in[0];
    // d_in[1] edge_index / d_in[2] batch are structurally known -> unused
    const float* ea    = (const float*)d_in[3];
    const float* W1    = (const float*)d_in[4];
    const float* b1    = (const float*)d_in[5];
    const float* W2    = (const float*)d_in[6];
    const float* b2    = (const float*)d_in[7];
    const float* W3    = (const float*)d_in[8];
    const float* b3    = (const float*)d_in[9];
    const float* W4    = (const float*)d_in[10];
    const float* b4    = (const float*)d_in[11];
    const float* cw    = (const float*)d_in[12];
    const float* cb    = (const float*)d_in[13];
    const float* gamma = (const float*)d_in[14];
    const float* beta  = (const float*)d_in[15];
    float* out = (float*)d_out;

    float* pT = (float*)d_ws;                    // [16*152][128] transposed pooled

    hipLaunchKernelGGL(gcn_kernel, dim3(GROUPS), dim3(128), 0, stream,
                       x, ea, W1, b1, W2, b2, W3, b3, W4, b4, pT);
    hipLaunchKernelGGL(conv_caps_kernel, dim3(16 * 34), dim3(512), 0, stream,
                       pT, cw, cb, gamma, beta, out);
}